// Round 9
// baseline (259.706 us; speedup 1.0000x reference)
//
#include <hip/hip_runtime.h>
#include <math.h>

#define B_BAGS 8
#define N_INST 8192
#define D_DIM  512
#define H_ATT  64
#define TOPK_K 2457
#define ROWS_TOTAL (B_BAGS * N_INST)

typedef __attribute__((ext_vector_type(8))) short bf16x8;
typedef __attribute__((ext_vector_type(4))) float f32x4;

// ---- workspace layout (bytes) ----
#define WS_W1P_HI 0                          // packed MFMA B-frags, 32768 ushort
#define WS_W1P_LO 65536                      // packed MFMA B-frags, 32768 ushort
#define WS_PART3  131584                     // [8][64][512] f32 gather partials (1 MB)
#define WS_PART1  (WS_PART3 + 8*64*512*4)    // [8kt][8b][512] f32 layer1 partials

__device__ __forceinline__ unsigned short bf16_rn(float f) {
  unsigned int x = __float_as_uint(f);
  unsigned int r = (x + 0x7FFFu + ((x >> 16) & 1u)) >> 16;
  return (unsigned short)r;
}
__device__ __forceinline__ float bf16_f(unsigned short u) {
  return __uint_as_float(((unsigned int)u) << 16);
}
__device__ __forceinline__ float gelu_f(float v) {
  float u = 0.7978845608028654f * (v + 0.044715f * v * v * v);
  return 0.5f * v * (1.0f + tanhf(u));
}

// truncation-based hi/lo split of 8 consecutive fp32 -> bf16x8 hi + lo.
__device__ __forceinline__ void cvt_hilo(const float4 u, const float4 v,
                                         bf16x8& h, bf16x8& l) {
  float f[8] = {u.x, u.y, u.z, u.w, v.x, v.y, v.z, v.w};
#pragma unroll
  for (int i = 0; i < 8; i++) {
    unsigned int b = __float_as_uint(f[i]);
    unsigned int hb = b & 0xFFFF0000u;
    float r = f[i] - __uint_as_float(hb);
    h[i] = (short)(b >> 16);
    l[i] = (short)(__float_as_uint(r) >> 16);
  }
}

// async global->LDS DMA, 16B per lane. LDS dest = wave-uniform base + lane*16.
__device__ __forceinline__ void load_lds16(const void* g, void* l) {
  __builtin_amdgcn_global_load_lds(
      (const __attribute__((address_space(1))) void*)g,
      (__attribute__((address_space(3))) void*)l, 16, 0, 0);
}

// ---------------- kernel 0: pack aW1 into MFMA-fragment-sequential layout ----
// Packed at offset ((ks*4 + t)*64 + lane)*8 + j -> B loads are lane-linear.
__global__ __launch_bounds__(256) void k_prep(const float* __restrict__ aW1,
                                              unsigned short* __restrict__ hi,
                                              unsigned short* __restrict__ lo) {
  int tau = blockIdx.x * 256 + threadIdx.x;   // (ks,t,lane) tuple, 4096 total
  if (tau >= 4096) return;
  int ks = tau >> 8, t = (tau >> 6) & 3, lane = tau & 63;
  int n = t * 16 + (lane & 15);
  int kb = ks * 32 + (lane >> 4) * 8;
#pragma unroll
  for (int j = 0; j < 8; j++) {
    float v = aW1[(kb + j) * H_ATT + n];
    unsigned short h = bf16_rn(v);
    unsigned short l = bf16_rn(v - bf16_f(h));
    hi[tau * 8 + j] = h;
    lo[tau * 8 + j] = l;
  }
}

// ---------------- kernel 1: score MLP -> sigmoid weights ----------------
// Per-CU vector-pipe model: minimize bytes through TA. BM=128 (512-thread
// blocks, 8 waves sharing one LDS-staged B chunk) halves per-CU B traffic
// vs BM=64. All staging via global_load_lds (no dest VGPRs). ~49 KB LDS ->
// 2-3 blocks/CU so drains overlap across blocks.
#define BM 128
#define AUNIT 1040   // 1024 + 16B pad (4 rows x 256B per unit)

__global__ __launch_bounds__(512) void k_scores(
    const float* __restrict__ x,
    const unsigned short* __restrict__ w1p_hi,
    const unsigned short* __restrict__ w1p_lo,
    const float* __restrict__ ab1, const float* __restrict__ aW2,
    const float* __restrict__ ab2, float* __restrict__ wout) {
  __shared__ __align__(16) char Asm[32 * AUNIT];   // 33,280 B
  __shared__ __align__(16) char Bh[8192];
  __shared__ __align__(16) char Bl[8192];

  int tid = threadIdx.x;               // 0..511
  int wave = tid >> 6, lane = tid & 63;
  int c0 = lane & 15, quad = lane >> 4;
  int rowBase0 = blockIdx.x * BM;

  f32x4 acc[4];
#pragma unroll
  for (int t = 0; t < 4; t++) acc[t] = (f32x4){0.f, 0.f, 0.f, 0.f};

  const int r = wave * 16 + c0;        // row within block this lane computes
  const int uA = r >> 2;
  const int aoff = uA * AUNIT + (r & 3) * 256 + quad * 32;

  for (int c = 0; c < 8; c++) {
    // ---- stage chunk c: A 32KB (32 instr, 4/wave) + B 16KB (16 instr, 2/wave)
    size_t kb = (size_t)c * 256;   // byte offset within a row (BK=64 fp32)
#pragma unroll
    for (int i = 0; i < 4; i++) {
      int u = wave * 4 + i;        // 0..31: unit of 4 rows
      const char* g = (const char*)x +
          (size_t)(rowBase0 + u * 4 + (lane >> 4)) * 2048 + kb + (size_t)(lane & 15) * 16;
      load_lds16(g, Asm + u * AUNIT);
    }
#pragma unroll
    for (int i = 0; i < 2; i++) {
      int v = wave * 2 + i;        // 0..15: 0-7 hi, 8-15 lo
      int vv = v & 7;
      const char* gsrc = (v < 8) ? (const char*)w1p_hi : (const char*)w1p_lo;
      char* ldst = (v < 8) ? Bh : Bl;
      load_lds16(gsrc + (size_t)c * 8192 + vv * 1024 + (size_t)lane * 16,
                 ldst + vv * 1024);
    }
    __syncthreads();   // drains DMA (vmcnt) + makes LDS visible

    // ---- compute chunk c: 2 k-steps ----
#pragma unroll
    for (int stp = 0; stp < 2; stp++) {
      const float4 a0v = *reinterpret_cast<const float4*>(Asm + aoff + stp * 128);
      const float4 a1v = *reinterpret_cast<const float4*>(Asm + aoff + stp * 128 + 16);
      bf16x8 afh, afl;
      cvt_hilo(a0v, a1v, afh, afl);
      bf16x8 bfh[4], bfl[4];
#pragma unroll
      for (int t = 0; t < 4; t++) {
        bfh[t] = *reinterpret_cast<const bf16x8*>(Bh + (stp * 4 + t) * 1024 + lane * 16);
        bfl[t] = *reinterpret_cast<const bf16x8*>(Bl + (stp * 4 + t) * 1024 + lane * 16);
      }
#pragma unroll
      for (int t = 0; t < 4; t++) {
        acc[t] = __builtin_amdgcn_mfma_f32_16x16x32_bf16(afl, bfh[t], acc[t], 0, 0, 0);
        acc[t] = __builtin_amdgcn_mfma_f32_16x16x32_bf16(afh, bfl[t], acc[t], 0, 0, 0);
        acc[t] = __builtin_amdgcn_mfma_f32_16x16x32_bf16(afh, bfh[t], acc[t], 0, 0, 0);
      }
    }
    __syncthreads();   // protect LDS before next chunk overwrites
  }

  // epilogue: h = gelu(acc + ab1); score = h @ aW2 + ab2; w = sigmoid(score)
  float w2v[4], b1v[4];
#pragma unroll
  for (int t = 0; t < 4; t++) {
    w2v[t] = aW2[t * 16 + c0];
    b1v[t] = ab1[t * 16 + c0];
  }
  float bias2 = ab2[0];
  float p[4] = {0.f, 0.f, 0.f, 0.f};
#pragma unroll
  for (int t = 0; t < 4; t++)
#pragma unroll
    for (int rr = 0; rr < 4; rr++) {
      float h = gelu_f(acc[t][rr] + b1v[t]);
      p[rr] += h * w2v[t];
    }
#pragma unroll
  for (int off = 1; off < 16; off <<= 1)
#pragma unroll
    for (int rr = 0; rr < 4; rr++) p[rr] += __shfl_xor(p[rr], off, 64);
  if (c0 == 0) {
    int row = rowBase0 + wave * 16 + quad * 4;
#pragma unroll
    for (int rr = 0; rr < 4; rr++) {
      float sc = p[rr] + bias2;
      wout[row + rr] = 1.0f / (1.0f + expf(-sc));
    }
  }
}

// ---------------- kernel 2: fused top-k + weighted gather ----------------
__global__ __launch_bounds__(256) void k_gather(const float* __restrict__ x,
                                                const float* __restrict__ wout,
                                                float* __restrict__ part3) {
  int b = blockIdx.x >> 6;
  int blk = blockIdx.x & 63;
  int tid = threadIdx.x;
  const float* w = wout + b * N_INST;

  unsigned int v[32];
#pragma unroll
  for (int j = 0; j < 32; j++) v[j] = __float_as_uint(w[j * 256 + tid]);

  __shared__ int red[2][4];
  int lane = tid & 63, wv = tid >> 6;
  int pb = 0;
  auto blocksum = [&](int c) -> int {
#pragma unroll
    for (int off = 32; off > 0; off >>= 1) c += __shfl_down(c, off, 64);
    if (lane == 0) red[pb][wv] = c;
    __syncthreads();
    int s = red[pb][0] + red[pb][1] + red[pb][2] + red[pb][3];
    pb ^= 1;
    return s;
  };

  unsigned int lo = 0u, hi = 0x3F800001u;
  while (hi - lo > 1u) {
    unsigned int mid = lo + ((hi - lo) >> 1);
    int c = 0;
#pragma unroll
    for (int j = 0; j < 32; j++) c += (v[j] >= mid) ? 1 : 0;
    if (blocksum(c) >= TOPK_K) lo = mid; else hi = mid;
  }
  unsigned int T = lo;
  int c1 = 0;
#pragma unroll
  for (int j = 0; j < 32; j++) c1 += (v[j] > T) ? 1 : 0;
  c1 = blocksum(c1);
  int needed = TOPK_K - c1;  // >= 1
  unsigned int tm = 0;
#pragma unroll
  for (int j = 0; j < 32; j++) tm |= (v[j] == T ? 1u : 0u) << j;
  int lom = -1, him = N_INST - 1;
  while (him - lom > 1) {
    int mid = (lom + him) >> 1;
    unsigned int mask = 0u;
    if (mid >= tid) {
      unsigned int jmax = (unsigned int)(mid - tid) >> 8;
      mask = (2u << jmax) - 1u;
    }
    if (blocksum((int)__popc(tm & mask)) >= needed) him = mid; else lom = mid;
  }
  int Icut = him;

  __shared__ int idxs[128];
  __shared__ float wgts[128];
  __shared__ int wcnt[2];
  __shared__ float4 xfer[128];

  int r = blk * 128 + tid;
  bool sel = false;
  float wvv = 0.f;
  int pos = 0;
  if (tid < 128) {
    wvv = w[r];
    unsigned int wu = __float_as_uint(wvv);
    sel = (wu > T) || (wu == T && r <= Icut);
    unsigned long long m = __ballot(sel);
    pos = __popcll(m & ((1ull << lane) - 1ull));
    if (lane == 0) wcnt[tid >> 6] = __popcll(m);
  }
  __syncthreads();
  int total = wcnt[0] + wcnt[1];
  if (sel) {
    int base = (tid >= 64) ? wcnt[0] : 0;
    idxs[base + pos] = r;
    wgts[base + pos] = wvv;
  }
  __syncthreads();

  int half = tid >> 7;
  int L = tid & 127;
  float4 acc = {0.f, 0.f, 0.f, 0.f};
  const float* xb = x + (size_t)b * N_INST * D_DIM;
  int i2 = total & ~1;
#pragma unroll 4
  for (int i = 0; i < i2; i += 2) {
    int rr = idxs[i + half];
    float ww = wgts[i + half];
    const float4 xv = *reinterpret_cast<const float4*>(xb + (size_t)rr * D_DIM + L * 4);
    acc.x += ww * xv.x; acc.y += ww * xv.y; acc.z += ww * xv.z; acc.w += ww * xv.w;
  }
  if ((total & 1) && half == 0) {
    int rr = idxs[i2];
    float ww = wgts[i2];
    const float4 xv = *reinterpret_cast<const float4*>(xb + (size_t)rr * D_DIM + L * 4);
    acc.x += ww * xv.x; acc.y += ww * xv.y; acc.z += ww * xv.z; acc.w += ww * xv.w;
  }
  if (half == 1) xfer[L] = acc;
  __syncthreads();
  if (half == 0) {
    float4 o = xfer[L];
    acc.x += o.x; acc.y += o.y; acc.z += o.z; acc.w += o.w;
    *reinterpret_cast<float4*>(part3 + (size_t)(b * 64 + blk) * D_DIM + L * 4) = acc;
  }
}

// ---------------- projection MLP: split-K; layer2 accumulates into out ----
__global__ __launch_bounds__(256) void k_proj1(const float* __restrict__ part3,
                                               const float* __restrict__ pW1,
                                               float* __restrict__ part1,
                                               const float* __restrict__ pb2,
                                               float* __restrict__ out) {
  int jt = blockIdx.x & 7, kt = blockIdx.x >> 3;
  __shared__ float emb_s[512];
  int tid = threadIdx.x;
  int col = tid & 63, bg = tid >> 6;
  if (kt == 0) {
    float bz = pb2[jt * 64 + col];
    out[(bg * 2) * 512 + jt * 64 + col] = bz;
    out[(bg * 2 + 1) * 512 + jt * 64 + col] = bz;
  }
#pragma unroll
  for (int h = 0; h < 2; h++) {
    int vi = tid + h * 256;
    int b = vi >> 6, d0 = vi & 63;
    const float* p = part3 + (size_t)b * 64 * 512 + kt * 64 + d0;
    float e = 0.f;
#pragma unroll 8
    for (int j = 0; j < 64; j++) e += p[j * 512];
    emb_s[vi] = e * (1.0f / TOPK_K);
  }
  __syncthreads();
  float a0 = 0.f, a1 = 0.f;
  const float* wrow = pW1 + (size_t)(kt * 64) * 512 + jt * 64 + col;
#pragma unroll 8
  for (int q = 0; q < 64; q++) {
    float wq = wrow[q * 512];
    a0 += emb_s[(bg * 2) * 64 + q] * wq;
    a1 += emb_s[(bg * 2 + 1) * 64 + q] * wq;
  }
  part1[kt * 4096 + (bg * 2) * 512 + jt * 64 + col] = a0;
  part1[kt * 4096 + (bg * 2 + 1) * 512 + jt * 64 + col] = a1;
}

__global__ __launch_bounds__(256) void k_proj2(const float* __restrict__ part1,
                                               const float* __restrict__ pb1,
                                               const float* __restrict__ pW2,
                                               float* __restrict__ out) {
  int jt = blockIdx.x & 7, kt = blockIdx.x >> 3;
  __shared__ float h_s[512];
  int tid = threadIdx.x;
#pragma unroll
  for (int h = 0; h < 2; h++) {
    int vi = tid + h * 256;
    int b = vi >> 6, j0 = vi & 63;
    int jj = kt * 64 + j0;
    float s = pb1[jj];
#pragma unroll
    for (int p = 0; p < 8; p++) s += part1[p * 4096 + b * 512 + jj];
    h_s[vi] = gelu_f(s);
  }
  __syncthreads();
  int col = tid & 63, bg = tid >> 6;
  float a0 = 0.f, a1 = 0.f;
  const float* wrow = pW2 + (size_t)(kt * 64) * 512 + jt * 64 + col;
#pragma unroll 8
  for (int q = 0; q < 64; q++) {
    float wq = wrow[q * 512];
    a0 += h_s[(bg * 2) * 64 + q] * wq;
    a1 += h_s[(bg * 2 + 1) * 64 + q] * wq;
  }
  atomicAdd(&out[(bg * 2) * 512 + jt * 64 + col], a0);
  atomicAdd(&out[(bg * 2 + 1) * 512 + jt * 64 + col], a1);
}

extern "C" void kernel_launch(void* const* d_in, const int* in_sizes, int n_in,
                              void* d_out, int out_size, void* d_ws, size_t ws_size,
                              hipStream_t stream) {
  (void)in_sizes; (void)n_in; (void)out_size; (void)ws_size;
  const float* x   = (const float*)d_in[0];
  const float* aW1 = (const float*)d_in[1];
  const float* ab1 = (const float*)d_in[2];
  const float* aW2 = (const float*)d_in[3];
  const float* ab2 = (const float*)d_in[4];
  const float* pW1 = (const float*)d_in[5];
  const float* pb1 = (const float*)d_in[6];
  const float* pW2 = (const float*)d_in[7];
  const float* pb2 = (const float*)d_in[8];

  float* out  = (float*)d_out;
  float* wout = out + B_BAGS * D_DIM;  // weights output region [8][8192]

  char* ws = (char*)d_ws;
  unsigned short* w1p_hi = (unsigned short*)(ws + WS_W1P_HI);
  unsigned short* w1p_lo = (unsigned short*)(ws + WS_W1P_LO);
  float* part3 = (float*)(ws + WS_PART3);
  float* part1 = (float*)(ws + WS_PART1);

  k_prep<<<dim3(16), dim3(256), 0, stream>>>(aW1, w1p_hi, w1p_lo);
  k_scores<<<dim3(ROWS_TOTAL / BM), dim3(512), 0, stream>>>(x, w1p_hi, w1p_lo, ab1, aW2, ab2, wout);
  k_gather<<<dim3(B_BAGS * 64), dim3(256), 0, stream>>>(x, wout, part3);
  k_proj1<<<dim3(64), dim3(256), 0, stream>>>(part3, pW1, part1, pb2, out);
  k_proj2<<<dim3(64), dim3(256), 0, stream>>>(part1, pb1, pW2, out);
}